// Round 9
// baseline (14444.875 us; speedup 1.0000x reference)
//
#include <hip/hip_runtime.h>
#include <hip/hip_cooperative_groups.h>
#include <math.h>

namespace cg = cooperative_groups;

#define NB 8
#define NV 64
#define NM 1024
#define NR 3
#define NT 16
#define KR 8
#define RTOT 48                 // NR*NT
#define RADIUSF 40.0f
#define TWO_PIF 6.283185307179586f

// ---------------------------------------------------------------------------
// Pair geometry: replicates the reference bilinear polar binning exactly.
// ---------------------------------------------------------------------------
__device__ __forceinline__ void pair_geom(float relx, float rely, float mask,
                                          float& valid, float& win,
                                          int bin[4], float cw[4]) {
    float d = sqrtf(relx * relx + rely * rely + 1e-12f);
    valid = (d < RADIUSF) ? mask : 0.0f;
    float q = d * (1.0f / RADIUSF);
    float w1 = fmaxf(1.0f - q * q, 0.0f);
    win = w1 * w1 * w1;
    float u = fminf(fmaxf(q, 0.0f), 1.0f) * (float)(NR - 1);
    float r0f = floorf(u);
    float wr = u - r0f;
    int r0 = (int)r0f;
    int r1 = min(r0 + 1, NR - 1);
    float a = atan2f(rely, relx) * (1.0f / TWO_PIF);
    a = a - floorf(a);                  // mod 1 -> [0,1)
    float t = a * (float)NT;
    float t0f = floorf(t);
    float wt = t - t0f;
    int t0 = ((int)t0f) & (NT - 1);
    int t1 = (t0 + 1) & (NT - 1);
    bin[0] = r0 * NT + t0; cw[0] = (1.0f - wr) * (1.0f - wt);
    bin[1] = r0 * NT + t1; cw[1] = (1.0f - wr) * wt;
    bin[2] = r1 * NT + t0; cw[2] = wr * (1.0f - wt);
    bin[3] = r1 * NT + t1; cw[3] = wr * wt;
}

// ---------------------------------------------------------------------------
// One-time K transpose: KT[chunk j][pair p].  [R6 verbatim]
// ---------------------------------------------------------------------------
__global__ __launch_bounds__(256) void k_trans(
        const float* __restrict__ Kv, const float* __restrict__ K1g,
        const float* __restrict__ K2g, float4* __restrict__ KTv,
        float4* __restrict__ KT1, float4* __restrict__ KT2) {
    int idx = blockIdx.x * 256 + threadIdx.x;
    if (idx < 48 * 384) {
        int j = idx / 384, p = idx % 384;
        KTv[idx] = *(const float4*)(Kv + p * 192 + j * 4);
    } else if (idx < 48 * 384 + 16 * 384) {
        int r = idx - 48 * 384;
        int j = r / 384, p = r % 384;
        KT1[r] = *(const float4*)(K1g + p * 64 + j * 4);
    } else if (idx < 48 * 384 + 16 * 384 + 16 * 144) {
        int r = idx - (48 * 384 + 16 * 384);
        int j = r / 144, p = r % 144;
        KT2[r] = *(const float4*)(K2g + p * 64 + j * 4);
    }
}

// ---------------------------------------------------------------------------
// PERSISTENT PATH: one cooperative kernel, all 30 steps, grid.sync barriers.
// Block bn=(b,n) keeps p (whole batch), feat/out1/out2/outD rows in LDS.
// Only H tensors and outD cross blocks (global, fenced + grid.sync).
// ---------------------------------------------------------------------------
__global__ __launch_bounds__(256, 2) void k_all(
        const float* __restrict__ in_p, const float* __restrict__ in_feat,
        const float* __restrict__ map_p, const float* __restrict__ map_feat,
        const float* __restrict__ car_mask, const float* __restrict__ map_mask,
        const float* __restrict__ WdV, const float* __restrict__ Wd1,
        const float* __restrict__ Wd2, const float* __restrict__ WdBack,
        const float* __restrict__ w_rho1, const float* __restrict__ Kmap,
        const float4* __restrict__ KTv, const float4* __restrict__ KT1,
        const float4* __restrict__ KT2,
        float* __restrict__ Hv, float* __restrict__ H1, float* __restrict__ H2,
        float* __restrict__ outD, float* __restrict__ out) {
    cg::grid_group grid = cg::this_grid();
    int tid = threadIdx.x;
    int bn = blockIdx.x, b = bn >> 6, n = bn & 63;

    __shared__ float s_psrc[NV * 2];
    __shared__ __align__(16) float s_feat[192];
    __shared__ float s_w[256];
    __shared__ int   s_row[256];
    __shared__ float s_out0[NV * KR];
    __shared__ float s_w2[16];
    __shared__ float s_G4[4 * 96];
    __shared__ float s_G[96];
    __shared__ float s_wred[4];
    __shared__ float s_part[4 * 64];
    __shared__ __align__(16) float s_o1[64];
    __shared__ __align__(16) float s_o2[64];
    __shared__ __align__(16) float s_oD[24];

    if (tid < 128) s_psrc[tid] = in_p[b * 128 + tid];
    if (tid < 192) s_feat[tid] = in_feat[bn * 192 + tid];
    if (tid >= 224 && tid < 240) {
        int r = tid - 224, m = r >> 1, dd = r & 1;
        float ang = TWO_PIF * (float)m / (float)KR;
        float sn, cs; sincosf(ang, &sn, &cs);
        float w0 = w_rho1[0], wq = w_rho1[1];
        s_w2[r] = (dd == 0) ? (w0 * cs - wq * sn) : (w0 * sn + wq * cs);
    }
    __syncthreads();

    for (int t = 0; t < 30; ++t) {
        if (t > 0) {
            // ---- advance: load outD ch0 of all sources; zero map accumulators
            for (int i = tid; i < NV * KR; i += 256)
                s_out0[i] = outD[(b * NV + (i >> 3)) * 24 + (i & 7)];
            if (tid < 96) { s_G4[tid] = 0.f; s_G4[96 + tid] = 0.f; s_G4[192 + tid] = 0.f; s_G4[288 + tid] = 0.f; }
            __syncthreads();
            // delta (regs) + outputs[t-1] (uses OLD p)
            float dx0 = 0.f, dy0 = 0.f;
            if (tid < NV) {
#pragma unroll
                for (int m = 0; m < KR; ++m) {
                    float v = s_out0[tid * KR + m];
                    dx0 = fmaf(v, s_w2[m * 2 + 0], dx0);
                    dy0 = fmaf(v, s_w2[m * 2 + 1], dy0);
                }
            }
            if (tid >= 64 && tid < 70) {
                int r = tid - 64, c = r >> 1, dd = r & 1;
                float acc = 0.f;
#pragma unroll
                for (int m = 0; m < KR; ++m)
                    acc = fmaf(s_oD[c * KR + m], s_w2[m * 2 + dd], acc);
                if (c == 0) acc += s_psrc[n * 2 + dd];
                out[(((t - 1) * NB + b) * NV + n) * 6 + c * 2 + dd] = acc;
            }
            __syncthreads();
            if (tid < NV) { s_psrc[tid * 2 + 0] += dx0; s_psrc[tid * 2 + 1] += dy0; }
            __syncthreads();
        }
        float pdx = s_psrc[n * 2 + 0], pdy = s_psrc[n * 2 + 1];
        // ---- pair weights (wave 0)
        if (tid < NV) {
            int s = tid;
            float valid, win; int bin[4]; float cw[4];
            pair_geom(s_psrc[s * 2 + 0] - pdx, s_psrc[s * 2 + 1] - pdy,
                      car_mask[b * NV + s], valid, win, bin, cw);
            float c = valid;
#pragma unroll
            for (int off = 32; off > 0; off >>= 1) c += __shfl_xor(c, off);
            float bw = valid * win / fmaxf(c, 1.0f);
#pragma unroll
            for (int q = 0; q < 4; ++q) {
                s_w[s * 4 + q] = bw * cw[q];
                s_row[s * 4 + q] = (b * NV + s) * RTOT + bin[q];
            }
        }
        if (t > 0) {
            // ---- map: single pass (unnormalized accumulate + count)
            float lc = 0.f;
            float* myG = &s_G4[(tid >> 6) * 96];
#pragma unroll
            for (int j = 0; j < NM / 256; ++j) {
                int s = tid + j * 256;
                float2 mp = *(const float2*)&map_p[(b * NM + s) * 2];
                float valid, win; int bin[4]; float cw[4];
                pair_geom(mp.x - pdx, mp.y - pdy, map_mask[b * NM + s], valid, win, bin, cw);
                lc += valid;
                float ww = valid * win;
                if (ww > 0.f) {
                    float2 f2 = *(const float2*)&map_feat[(b * NM + s) * 2];
#pragma unroll
                    for (int q = 0; q < 4; ++q) {
                        float w = ww * cw[q];
                        atomicAdd(&myG[bin[q] * 2 + 0], w * f2.x);
                        atomicAdd(&myG[bin[q] * 2 + 1], w * f2.y);
                    }
                }
            }
#pragma unroll
            for (int off = 32; off > 0; off >>= 1) lc += __shfl_xor(lc, off);
            if ((tid & 63) == 0) s_wred[tid >> 6] = lc;
            __syncthreads();
            if (tid < 96) s_G[tid] = s_G4[tid] + s_G4[96 + tid] + s_G4[192 + tid] + s_G4[288 + tid];
            __syncthreads();
            float invc = 1.0f / fmaxf(s_wred[0] + s_wred[1] + s_wred[2] + s_wred[3], 1.0f);
            // map encoder contraction (Kmap direct, coalesced float2)
            if (tid < 64) {
                float acc = 0.f;
#pragma unroll 4
                for (int rt = 0; rt < RTOT; ++rt) {
                    float2 k2 = *(const float2*)&Kmap[(rt * 64 + tid) * 2];
                    acc = fmaf(k2.x, s_G[rt * 2 + 0], acc);
                    acc = fmaf(k2.y, s_G[rt * 2 + 1], acc);
                }
                s_feat[128 + tid] = fmaxf(acc * invc, 0.f);
            }
            // back gate on feat[0..127]
            if (tid >= 128) {
                int r = tid - 128, i = r >> 3, m = r & 7;
                float acc = 0.f;
#pragma unroll
                for (int c = 0; c < 3; ++c)
#pragma unroll
                    for (int l = 0; l < KR; ++l)
                        acc = fmaf(WdBack[(i * 3 + c) * 8 + l], s_oD[c * 8 + ((m - l) & 7)], acc);
                s_feat[r] = s_feat[r] * tanhf(acc);
            }
        }
        __syncthreads();
        // ---- Hv from s_feat (own source row)
        for (int p = tid; p < 384; p += 256) {
            float acc[KR];
#pragma unroll
            for (int m = 0; m < KR; ++m) acc[m] = 0.f;
#pragma unroll 4
            for (int i = 0; i < 24; ++i) {
                float4 k0 = KTv[(2 * i) * 384 + p];
                float4 k1 = KTv[(2 * i + 1) * 384 + p];
                float kk[8] = {k0.x, k0.y, k0.z, k0.w, k1.x, k1.y, k1.z, k1.w};
                float ff[8];
                *(float4*)&ff[0] = *(const float4*)&s_feat[i * 8];
                *(float4*)&ff[4] = *(const float4*)&s_feat[i * 8 + 4];
#pragma unroll
                for (int l = 0; l < KR; ++l) {
                    float kl = kk[l];
#pragma unroll
                    for (int m = 0; m < KR; ++m)
                        acc[m] = fmaf(kl, ff[(m - l) & 7], acc[m]);
                }
            }
            int rt = p >> 3, o = p & 7;
            float* hr = Hv + (size_t)(bn * RTOT + rt) * 64 + o * KR;
#pragma unroll
            for (int m = 0; m < KR; ++m) hr[m] = acc[m];
        }
        __threadfence();
        grid.sync();
        // ---- layer 1: aggregate Hv + equilinear(WdV, feat) -> o1; H1 from relu(o1)
        {
            int w = tid >> 6, c = tid & 63;
            float acc = 0.f;
#pragma unroll 8
            for (int j = 0; j < 64; ++j) {
                int idx = w * 64 + j;
                acc = fmaf(s_w[idx], Hv[(size_t)s_row[idx] * 64 + c], acc);
            }
            s_part[w * 64 + c] = acc;
        }
        __syncthreads();
        if (tid < 64) {
            float tot = s_part[tid] + s_part[64 + tid] + s_part[128 + tid] + s_part[192 + tid];
            int o = tid >> 3, m = tid & 7;
#pragma unroll
            for (int i = 0; i < 24; ++i) {
                const float* Wr = WdV + (o * 24 + i) * KR;
#pragma unroll
                for (int l = 0; l < KR; ++l)
                    tot = fmaf(Wr[l], s_feat[i * KR + ((m - l) & 7)], tot);
            }
            s_o1[tid] = tot;
        }
        __syncthreads();
        for (int p = tid; p < 384; p += 256) {
            float acc[KR];
#pragma unroll
            for (int m = 0; m < KR; ++m) acc[m] = 0.f;
#pragma unroll 2
            for (int i = 0; i < 8; ++i) {
                float4 k0 = KT1[(2 * i) * 384 + p];
                float4 k1 = KT1[(2 * i + 1) * 384 + p];
                float kk[8] = {k0.x, k0.y, k0.z, k0.w, k1.x, k1.y, k1.z, k1.w};
                float ff[8];
#pragma unroll
                for (int m = 0; m < KR; ++m) ff[m] = fmaxf(s_o1[i * 8 + m], 0.f);
#pragma unroll
                for (int l = 0; l < KR; ++l) {
                    float kl = kk[l];
#pragma unroll
                    for (int m = 0; m < KR; ++m)
                        acc[m] = fmaf(kl, ff[(m - l) & 7], acc[m]);
                }
            }
            int rt = p >> 3, o = p & 7;
            float* hr = H1 + (size_t)(bn * RTOT + rt) * 64 + o * KR;
#pragma unroll
            for (int m = 0; m < KR; ++m) hr[m] = acc[m];
        }
        __threadfence();
        grid.sync();
        // ---- layer 2: aggregate H1 + equilinear(Wd1, relu(o1)) + o1 -> o2; H2 from relu(o2)
        {
            int w = tid >> 6, c = tid & 63;
            float acc = 0.f;
#pragma unroll 8
            for (int j = 0; j < 64; ++j) {
                int idx = w * 64 + j;
                acc = fmaf(s_w[idx], H1[(size_t)s_row[idx] * 64 + c], acc);
            }
            s_part[w * 64 + c] = acc;
        }
        __syncthreads();
        if (tid < 64) {
            float tot = s_part[tid] + s_part[64 + tid] + s_part[128 + tid] + s_part[192 + tid];
            int o = tid >> 3, m = tid & 7;
#pragma unroll
            for (int i = 0; i < 8; ++i) {
                const float* Wr = Wd1 + (o * 8 + i) * KR;
#pragma unroll
                for (int l = 0; l < KR; ++l)
                    tot = fmaf(Wr[l], fmaxf(s_o1[i * KR + ((m - l) & 7)], 0.f), tot);
            }
            tot += s_o1[tid];
            s_o2[tid] = tot;
        }
        __syncthreads();
        for (int p = tid; p < 144; p += 256) {
            float acc[KR];
#pragma unroll
            for (int m = 0; m < KR; ++m) acc[m] = 0.f;
#pragma unroll 2
            for (int i = 0; i < 8; ++i) {
                float4 k0 = KT2[(2 * i) * 144 + p];
                float4 k1 = KT2[(2 * i + 1) * 144 + p];
                float kk[8] = {k0.x, k0.y, k0.z, k0.w, k1.x, k1.y, k1.z, k1.w};
                float ff[8];
#pragma unroll
                for (int m = 0; m < KR; ++m) ff[m] = fmaxf(s_o2[i * 8 + m], 0.f);
#pragma unroll
                for (int l = 0; l < KR; ++l) {
                    float kl = kk[l];
#pragma unroll
                    for (int m = 0; m < KR; ++m)
                        acc[m] = fmaf(kl, ff[(m - l) & 7], acc[m]);
                }
            }
            int rt = p / 3, o = p - rt * 3;
            float* hr = H2 + (size_t)(bn * RTOT + rt) * 24 + o * KR;
#pragma unroll
            for (int m = 0; m < KR; ++m) hr[m] = acc[m];
        }
        __threadfence();
        grid.sync();
        // ---- layer 3: aggregate H2 + equilinear(Wd2, relu(o2)); relu -> outD
        {
            int w = tid >> 6, c = tid & 63;
            if (c < 24) {
                float acc = 0.f;
#pragma unroll 8
                for (int j = 0; j < 64; ++j) {
                    int idx = w * 64 + j;
                    acc = fmaf(s_w[idx], H2[(size_t)s_row[idx] * 24 + c], acc);
                }
                s_part[w * 24 + c] = acc;
            }
        }
        __syncthreads();
        if (tid < 24) {
            float tot = s_part[tid] + s_part[24 + tid] + s_part[48 + tid] + s_part[72 + tid];
            int o = tid / KR, m = tid & 7;
#pragma unroll
            for (int i = 0; i < 8; ++i) {
                const float* Wr = Wd2 + (o * 8 + i) * KR;
#pragma unroll
                for (int l = 0; l < KR; ++l)
                    tot = fmaf(Wr[l], fmaxf(s_o2[i * KR + ((m - l) & 7)], 0.f), tot);
            }
            tot = fmaxf(tot, 0.f);
            s_oD[tid] = tot;
            outD[bn * 24 + tid] = tot;
        }
        __threadfence();
        grid.sync();
    }
    // ---- final: outputs[29] = reg2rho1(outD_29) + p_29 (chan 0)
    if (tid < 6) {
        int c = tid >> 1, dd = tid & 1;
        float acc = 0.f;
#pragma unroll
        for (int m = 0; m < KR; ++m)
            acc = fmaf(s_oD[c * KR + m], s_w2[m * 2 + dd], acc);
        if (c == 0) acc += s_psrc[n * 2 + dd];
        out[((29 * NB + b) * NV + n) * 6 + c * 2 + dd] = acc;
    }
}

// ===========================================================================
// FALLBACK PATH (R8 verbatim): multi-kernel sequence, proven at 1.86 ms.
// ===========================================================================
__global__ __launch_bounds__(64) void k_pairs0(const float* __restrict__ p,
                                               const float* __restrict__ car_mask,
                                               float* __restrict__ w4,
                                               int* __restrict__ bin4) {
    int b = blockIdx.x >> 6, n = blockIdx.x & 63;
    int s = threadIdx.x;
    float dx = p[(b * NV + n) * 2 + 0], dy = p[(b * NV + n) * 2 + 1];
    float relx = p[(b * NV + s) * 2 + 0] - dx;
    float rely = p[(b * NV + s) * 2 + 1] - dy;
    float valid, win; int bin[4]; float cw[4];
    pair_geom(relx, rely, car_mask[b * NV + s], valid, win, bin, cw);
    float c = valid;
#pragma unroll
    for (int off = 32; off > 0; off >>= 1) c += __shfl_xor(c, off);
    float bw = valid * win / fmaxf(c, 1.0f);
    int base = (blockIdx.x * NV + s) * 4;
#pragma unroll
    for (int q = 0; q < 4; ++q) { w4[base + q] = bw * cw[q]; bin4[base + q] = bin[q]; }
}

__global__ __launch_bounds__(256) void k_advHv(int t,
        const float* __restrict__ pprev, float* __restrict__ pcur,
        const float* __restrict__ outD, float* __restrict__ feat,
        const float* __restrict__ w_rho1, const float* __restrict__ WdBack,
        const float* __restrict__ Kmap, const float* __restrict__ map_p,
        const float* __restrict__ map_feat, const float* __restrict__ map_mask,
        const float* __restrict__ car_mask,
        float* __restrict__ w4, int* __restrict__ bin4,
        float* __restrict__ out,
        const float4* __restrict__ KTv, float* __restrict__ Hv, int doHv) {
    __shared__ float s_out0[NV * KR];
    __shared__ float s_own[3 * KR];
    __shared__ float s_psrc[NV * 2];
    __shared__ float s_G4[4 * 96];
    __shared__ float s_G[96];
    __shared__ float s_wred[4];
    __shared__ float s_w2[KR * 2];
    __shared__ __align__(16) float s_f2[192];

    int tid = threadIdx.x;
    int bn = blockIdx.x, b = bn >> 6, n = bn & 63;

    for (int i = tid; i < NV * KR; i += 256)
        s_out0[i] = outD[(b * NV + (i >> 3)) * 24 + (i & 7)];
    if (tid < 24) s_own[tid] = outD[(b * NV + n) * 24 + tid];
    if (tid >= 32 && tid < 48) {
        int r = tid - 32, m = r >> 1, dd = r & 1;
        float ang = TWO_PIF * (float)m / (float)KR;
        float sn, cs; sincosf(ang, &sn, &cs);
        float w0 = w_rho1[0], wq = w_rho1[1];
        s_w2[r] = (dd == 0) ? (w0 * cs - wq * sn) : (w0 * sn + wq * cs);
    }
    if (tid < 96) { s_G4[tid] = 0.f; s_G4[96 + tid] = 0.f; s_G4[192 + tid] = 0.f; s_G4[288 + tid] = 0.f; }
    __syncthreads();

    if (tid < NV) {
        int s = tid;
        float dx0 = 0.0f, dy0 = 0.0f;
#pragma unroll
        for (int m = 0; m < KR; ++m) {
            float v = s_out0[s * KR + m];
            dx0 = fmaf(v, s_w2[m * 2 + 0], dx0);
            dy0 = fmaf(v, s_w2[m * 2 + 1], dy0);
        }
        s_psrc[s * 2 + 0] = pprev[(b * NV + s) * 2 + 0] + dx0;
        s_psrc[s * 2 + 1] = pprev[(b * NV + s) * 2 + 1] + dy0;
    }
    if (tid >= 64 && tid < 70) {
        int r = tid - 64, c = r >> 1, dd = r & 1;
        float acc = 0.0f;
#pragma unroll
        for (int m = 0; m < KR; ++m)
            acc = fmaf(s_own[c * KR + m], s_w2[m * 2 + dd], acc);
        if (c == 0) acc += pprev[(b * NV + n) * 2 + dd];
        out[(((t - 1) * NB + b) * NV + n) * 6 + c * 2 + dd] = acc;
    }
    __syncthreads();
    if (tid < 2) pcur[(b * NV + n) * 2 + tid] = s_psrc[n * 2 + tid];

    float pdx = s_psrc[n * 2 + 0], pdy = s_psrc[n * 2 + 1];

    if (tid < NV) {
        int s = tid;
        float valid, win; int bin[4]; float cw[4];
        pair_geom(s_psrc[s * 2 + 0] - pdx, s_psrc[s * 2 + 1] - pdy,
                  car_mask[b * NV + s], valid, win, bin, cw);
        float c = valid;
#pragma unroll
        for (int off = 32; off > 0; off >>= 1) c += __shfl_xor(c, off);
        float bw = valid * win / fmaxf(c, 1.0f);
        int base = (bn * NV + s) * 4;
#pragma unroll
        for (int q = 0; q < 4; ++q) { w4[base + q] = bw * cw[q]; bin4[base + q] = bin[q]; }
    }

    float lc = 0.0f;
    float* myG = &s_G4[(tid >> 6) * 96];
#pragma unroll
    for (int j = 0; j < NM / 256; ++j) {
        int s = tid + j * 256;
        float2 mp = *(const float2*)&map_p[(b * NM + s) * 2];
        float valid, win; int bin[4]; float cw[4];
        pair_geom(mp.x - pdx, mp.y - pdy, map_mask[b * NM + s], valid, win, bin, cw);
        lc += valid;
        float ww = valid * win;
        if (ww > 0.0f) {
            float2 f2 = *(const float2*)&map_feat[(b * NM + s) * 2];
#pragma unroll
            for (int q = 0; q < 4; ++q) {
                float w = ww * cw[q];
                atomicAdd(&myG[bin[q] * 2 + 0], w * f2.x);
                atomicAdd(&myG[bin[q] * 2 + 1], w * f2.y);
            }
        }
    }
#pragma unroll
    for (int off = 32; off > 0; off >>= 1) lc += __shfl_xor(lc, off);
    if ((tid & 63) == 0) s_wred[tid >> 6] = lc;
    __syncthreads();
    if (tid < 96) s_G[tid] = s_G4[tid] + s_G4[96 + tid] + s_G4[192 + tid] + s_G4[288 + tid];
    __syncthreads();
    float invc = 1.0f / fmaxf(s_wred[0] + s_wred[1] + s_wred[2] + s_wred[3], 1.0f);

    if (tid < 64) {
        float acc = 0.0f;
#pragma unroll 4
        for (int rt = 0; rt < RTOT; ++rt) {
            float2 k2 = *(const float2*)&Kmap[(rt * 64 + tid) * 2];
            acc = fmaf(k2.x, s_G[rt * 2 + 0], acc);
            acc = fmaf(k2.y, s_G[rt * 2 + 1], acc);
        }
        s_f2[128 + tid] = fmaxf(acc * invc, 0.0f);
    }
    if (tid >= 128) {
        int r = tid - 128, i = r >> 3, m = r & 7;
        float acc = 0.0f;
#pragma unroll
        for (int c = 0; c < 3; ++c)
#pragma unroll
            for (int l = 0; l < KR; ++l)
                acc = fmaf(WdBack[(i * 3 + c) * 8 + l], s_own[c * 8 + ((m - l) & 7)], acc);
        s_f2[r] = feat[(b * NV + n) * 192 + r] * tanhf(acc);
    }
    __syncthreads();
    if (tid < 192) feat[bn * 192 + tid] = s_f2[tid];

    if (doHv) {
        for (int p = tid; p < 384; p += 256) {
            float acc[KR];
#pragma unroll
            for (int m = 0; m < KR; ++m) acc[m] = 0.f;
#pragma unroll 4
            for (int i = 0; i < 24; ++i) {
                float4 k0 = KTv[(2 * i) * 384 + p];
                float4 k1 = KTv[(2 * i + 1) * 384 + p];
                float kk[8] = {k0.x, k0.y, k0.z, k0.w, k1.x, k1.y, k1.z, k1.w};
                float ff[8];
                *(float4*)&ff[0] = *(const float4*)&s_f2[i * 8];
                *(float4*)&ff[4] = *(const float4*)&s_f2[i * 8 + 4];
#pragma unroll
                for (int l = 0; l < KR; ++l) {
                    float kl = kk[l];
#pragma unroll
                    for (int m = 0; m < KR; ++m)
                        acc[m] = fmaf(kl, ff[(m - l) & 7], acc[m]);
                }
            }
            int rt = p >> 3, o = p & 7;
            float* hr = Hv + (size_t)(bn * RTOT + rt) * 64 + o * KR;
#pragma unroll
            for (int m = 0; m < KR; ++m) hr[m] = acc[m];
        }
    }
}

__global__ __launch_bounds__(256) void k_H0(const float* __restrict__ inb,
        const float4* __restrict__ KT, float* __restrict__ H) {
    __shared__ __align__(16) float s_f[192];
    int bs = blockIdx.x, tid = threadIdx.x;
    if (tid < 192) s_f[tid] = inb[bs * 192 + tid];
    __syncthreads();
    for (int p = tid; p < 384; p += 256) {
        float acc[KR];
#pragma unroll
        for (int m = 0; m < KR; ++m) acc[m] = 0.f;
#pragma unroll 4
        for (int i = 0; i < 24; ++i) {
            float4 k0 = KT[(2 * i) * 384 + p];
            float4 k1 = KT[(2 * i + 1) * 384 + p];
            float kk[8] = {k0.x, k0.y, k0.z, k0.w, k1.x, k1.y, k1.z, k1.w};
            float ff[8];
            *(float4*)&ff[0] = *(const float4*)&s_f[i * 8];
            *(float4*)&ff[4] = *(const float4*)&s_f[i * 8 + 4];
#pragma unroll
            for (int l = 0; l < KR; ++l) {
                float kl = kk[l];
#pragma unroll
                for (int m = 0; m < KR; ++m)
                    acc[m] = fmaf(kl, ff[(m - l) & 7], acc[m]);
            }
        }
        int rt = p >> 3, o = p & 7;
        float* hr = H + (size_t)(bs * RTOT + rt) * 64 + o * KR;
#pragma unroll
        for (int m = 0; m < KR; ++m) hr[m] = acc[m];
    }
}

template<int ICH, bool RELU_IN, bool RESID, int OCH2>
__global__ __launch_bounds__(256) void k_aggH(const float* __restrict__ inb,
        const float* __restrict__ H, const float* __restrict__ Wd,
        const float* __restrict__ w4, const int* __restrict__ bin4,
        const float4* __restrict__ KT2, float* __restrict__ outb,
        float* __restrict__ Hout) {
    constexpr int NC = ICH * KR;
    constexpr int HS = 64;
    constexpr int NPAIR2 = RTOT * OCH2;
    constexpr int HS2 = OCH2 * KR;
    __shared__ float s_w[256];
    __shared__ int   s_row[256];
    __shared__ float s_in[NC];
    __shared__ float s_part[4 * HS];
    __shared__ __align__(16) float s_f2[HS];
    int tid = threadIdx.x, bn = blockIdx.x, b = bn >> 6;
    s_w[tid] = w4[bn * 256 + tid];
    s_row[tid] = (b * NV + (tid >> 2)) * RTOT + bin4[bn * 256 + tid];
    if (tid < NC) s_in[tid] = inb[bn * NC + tid];
    __syncthreads();
    {
        int w = tid >> 6, c = tid & 63;
        float acc = 0.f;
#pragma unroll 8
        for (int j = 0; j < 64; ++j) {
            int idx = w * 64 + j;
            acc = fmaf(s_w[idx], H[(size_t)s_row[idx] * HS + c], acc);
        }
        s_part[w * HS + c] = acc;
    }
    __syncthreads();
    if (tid < HS) {
        float tot = s_part[tid] + s_part[HS + tid] + s_part[2 * HS + tid] + s_part[3 * HS + tid];
        int o = tid / KR, m = tid & 7;
#pragma unroll
        for (int i = 0; i < ICH; ++i) {
            const float* Wr = Wd + (o * ICH + i) * KR;
#pragma unroll
            for (int l = 0; l < KR; ++l) {
                float v = s_in[i * KR + ((m - l) & 7)];
                if (RELU_IN) v = fmaxf(v, 0.f);
                tot = fmaf(Wr[l], v, tot);
            }
        }
        if (RESID) tot += s_in[tid];
        outb[bn * HS + tid] = tot;
        s_f2[tid] = fmaxf(tot, 0.f);
    }
    __syncthreads();
    for (int p = tid; p < NPAIR2; p += 256) {
        float acc2[KR];
#pragma unroll
        for (int m = 0; m < KR; ++m) acc2[m] = 0.f;
#pragma unroll 2
        for (int i = 0; i < 8; ++i) {
            float4 k0 = KT2[(2 * i) * NPAIR2 + p];
            float4 k1 = KT2[(2 * i + 1) * NPAIR2 + p];
            float kk[8] = {k0.x, k0.y, k0.z, k0.w, k1.x, k1.y, k1.z, k1.w};
            float ff[8];
            *(float4*)&ff[0] = *(const float4*)&s_f2[i * 8];
            *(float4*)&ff[4] = *(const float4*)&s_f2[i * 8 + 4];
#pragma unroll
            for (int l = 0; l < KR; ++l) {
                float kl = kk[l];
#pragma unroll
                for (int m = 0; m < KR; ++m)
                    acc2[m] = fmaf(kl, ff[(m - l) & 7], acc2[m]);
            }
        }
        int rt = p / OCH2, o = p - rt * OCH2;
        float* hr = Hout + (size_t)(bn * RTOT + rt) * HS2 + o * KR;
#pragma unroll
        for (int m = 0; m < KR; ++m) hr[m] = acc2[m];
    }
}

template<int ICH, int OCH, bool RELU_IN, bool RESID, bool RELU_OUT>
__global__ __launch_bounds__(256) void k_agg(const float* __restrict__ inb,
        const float* __restrict__ H, const float* __restrict__ Wd,
        const float* __restrict__ w4, const int* __restrict__ bin4,
        float* __restrict__ outb) {
    constexpr int NC = ICH * KR;
    constexpr int HS = OCH * KR;
    __shared__ float s_w[256];
    __shared__ int   s_row[256];
    __shared__ float s_in[NC];
    __shared__ float s_part[4 * HS];
    int tid = threadIdx.x, bn = blockIdx.x, b = bn >> 6;
    s_w[tid] = w4[bn * 256 + tid];
    s_row[tid] = (b * NV + (tid >> 2)) * RTOT + bin4[bn * 256 + tid];
    if (tid < NC) s_in[tid] = inb[bn * NC + tid];
    __syncthreads();
    int w = tid >> 6, c = tid & 63;
    if (c < HS) {
        float acc = 0.f;
#pragma unroll 8
        for (int j = 0; j < 64; ++j) {
            int idx = w * 64 + j;
            acc = fmaf(s_w[idx], H[(size_t)s_row[idx] * HS + c], acc);
        }
        s_part[w * HS + c] = acc;
    }
    __syncthreads();
    if (tid < HS) {
        float tot = s_part[tid] + s_part[HS + tid] + s_part[2 * HS + tid] + s_part[3 * HS + tid];
        int o = tid / KR, m = tid & 7;
#pragma unroll
        for (int i = 0; i < ICH; ++i) {
            const float* Wr = Wd + (o * ICH + i) * KR;
#pragma unroll
            for (int l = 0; l < KR; ++l) {
                float v = s_in[i * KR + ((m - l) & 7)];
                if (RELU_IN) v = fmaxf(v, 0.f);
                tot = fmaf(Wr[l], v, tot);
            }
        }
        if (RESID) tot += s_in[tid];
        if (RELU_OUT) tot = fmaxf(tot, 0.f);
        outb[bn * HS + tid] = tot;
    }
}

__global__ void k_final(const float* __restrict__ outD, const float* __restrict__ pcur,
                        const float* __restrict__ w_rho1, float* __restrict__ out) {
    int idx = blockIdx.x * blockDim.x + threadIdx.x;
    if (idx >= NB * NV * 6) return;
    int bn = idx / 6, r = idx % 6, c = r >> 1, dd = r & 1;
    float w0 = w_rho1[0], wq = w_rho1[1];
    float acc = 0.0f;
#pragma unroll
    for (int m = 0; m < KR; ++m) {
        float ang = TWO_PIF * (float)m / (float)KR;
        float sn, cs; sincosf(ang, &sn, &cs);
        float w2 = (dd == 0) ? (w0 * cs - wq * sn) : (w0 * sn + wq * cs);
        acc = fmaf(outD[bn * 24 + c * 8 + m], w2, acc);
    }
    if (c == 0) acc += pcur[bn * 2 + dd];
    out[(29 * NB * NV + bn) * 6 + r] = acc;
}

// ---------------------------------------------------------------------------
extern "C" void kernel_launch(void* const* d_in, const int* in_sizes, int n_in,
                              void* d_out, int out_size, void* d_ws, size_t ws_size,
                              hipStream_t stream) {
    const float* in_p     = (const float*)d_in[0];
    const float* in_feat  = (const float*)d_in[1];
    const float* map_p    = (const float*)d_in[2];
    const float* map_feat = (const float*)d_in[3];
    const float* car_mask = (const float*)d_in[4];
    const float* map_mask = (const float*)d_in[5];
    const float* Kv       = (const float*)d_in[6];
    const float* WdV      = (const float*)d_in[7];
    const float* K1       = (const float*)d_in[8];
    const float* Wd1      = (const float*)d_in[9];
    const float* K2       = (const float*)d_in[10];
    const float* Wd2      = (const float*)d_in[11];
    const float* WdBack   = (const float*)d_in[12];
    const float* w_rho1   = (const float*)d_in[13];
    const float* Kmap     = (const float*)d_in[14];

    float* ws   = (float*)d_ws;
    float* pbuf0 = ws;                       // 1024
    float* pbuf1 = ws + 1024;                // 1024
    float* feat  = ws + 2048;                // 98304  [512][192]
    float* out1  = ws + 100352;              // 32768
    float* out2  = ws + 133120;              // 32768
    float* outD  = ws + 165888;              // 12288  [512][24]
    float* w4    = ws + 178176;              // 131072
    int*   bin4  = (int*)(ws + 309248);      // 131072 ints
    float4* KTv  = (float4*)(ws + 440320);   // 73728 floats
    float4* KT1  = (float4*)(ws + 514048);   // 24576 floats
    float4* KT2  = (float4*)(ws + 538624);   // 9216 floats
    float* Hv    = ws + 547840;              // 1572864 [512][48][64]
    float* H1    = ws + 2120704;             // 1572864
    float* H2    = ws + 3693568;             // 589824  [512][48][24]
    float* out   = (float*)d_out;

    const size_t need_fast = (size_t)(3693568 + 589824) * sizeof(float); // 17.1 MB
    const bool fast = ws_size >= need_fast;

    bool done = false;
    if (fast) {
        k_trans<<<105, 256, 0, stream>>>(Kv, K1, K2, KTv, KT1, KT2);
        const float4* KTv_c = KTv; const float4* KT1_c = KT1; const float4* KT2_c = KT2;
        void* kargs[] = {
            (void*)&in_p, (void*)&in_feat, (void*)&map_p, (void*)&map_feat,
            (void*)&car_mask, (void*)&map_mask, (void*)&WdV, (void*)&Wd1,
            (void*)&Wd2, (void*)&WdBack, (void*)&w_rho1, (void*)&Kmap,
            (void*)&KTv_c, (void*)&KT1_c, (void*)&KT2_c,
            (void*)&Hv, (void*)&H1, (void*)&H2, (void*)&outD, (void*)&out };
        hipError_t e = hipLaunchCooperativeKernel((const void*)k_all,
                dim3(NB * NV), dim3(256), kargs, 0, stream);
        done = (e == hipSuccess);
    }
    if (!done) {
        // R8-proven multi-kernel fallback
        hipMemcpyAsync(pbuf0, in_p, NB * NV * 2 * sizeof(float),
                       hipMemcpyDeviceToDevice, stream);
        hipMemcpyAsync(feat, in_feat, NB * NV * 24 * KR * sizeof(float),
                       hipMemcpyDeviceToDevice, stream);
        if (!fast)
            k_trans<<<105, 256, 0, stream>>>(Kv, K1, K2, KTv, KT1, KT2);
        k_pairs0<<<NB * NV, 64, 0, stream>>>(pbuf0, car_mask, w4, bin4);
        auto decode_fast = [&]() {
            k_aggH<24, false, false, 8><<<NB * NV, 256, 0, stream>>>(feat, Hv, WdV, w4, bin4, KT1, out1, H1);
            k_aggH<8, true, true, 3><<<NB * NV, 256, 0, stream>>>(out1, H1, Wd1, w4, bin4, KT2, out2, H2);
            k_agg<8, 3, true, false, true><<<NB * NV, 256, 0, stream>>>(out2, H2, Wd2, w4, bin4, outD);
        };
        k_H0<<<NB * NV, 256, 0, stream>>>(feat, KTv, Hv);
        decode_fast();
        for (int t = 1; t < 30; ++t) {
            float* pprev = (t & 1) ? pbuf0 : pbuf1;
            float* pcur  = (t & 1) ? pbuf1 : pbuf0;
            k_advHv<<<NB * NV, 256, 0, stream>>>(t, pprev, pcur, outD, feat,
                                                 w_rho1, WdBack, Kmap, map_p, map_feat,
                                                 map_mask, car_mask, w4, bin4, out,
                                                 KTv, Hv, 1);
            decode_fast();
        }
        k_final<<<12, 256, 0, stream>>>(outD, pbuf1, w_rho1, out);
    }
}

// Round 10
// 1764.771 us; speedup vs baseline: 8.1851x; 8.1851x over previous
//
#include <hip/hip_runtime.h>
#include <math.h>

#define NB 8
#define NV 64
#define NM 1024
#define NR 3
#define NT 16
#define KR 8
#define RTOT 48                 // NR*NT
#define RADIUSF 40.0f
#define TWO_PIF 6.283185307179586f

// ---------------------------------------------------------------------------
// Pair geometry: replicates the reference bilinear polar binning exactly.
// ---------------------------------------------------------------------------
__device__ __forceinline__ void pair_geom(float relx, float rely, float mask,
                                          float& valid, float& win,
                                          int bin[4], float cw[4]) {
    float d = sqrtf(relx * relx + rely * rely + 1e-12f);
    valid = (d < RADIUSF) ? mask : 0.0f;
    float q = d * (1.0f / RADIUSF);
    float w1 = fmaxf(1.0f - q * q, 0.0f);
    win = w1 * w1 * w1;
    float u = fminf(fmaxf(q, 0.0f), 1.0f) * (float)(NR - 1);
    float r0f = floorf(u);
    float wr = u - r0f;
    int r0 = (int)r0f;
    int r1 = min(r0 + 1, NR - 1);
    float a = atan2f(rely, relx) * (1.0f / TWO_PIF);
    a = a - floorf(a);                  // mod 1 -> [0,1)
    float t = a * (float)NT;
    float t0f = floorf(t);
    float wt = t - t0f;
    int t0 = ((int)t0f) & (NT - 1);
    int t1 = (t0 + 1) & (NT - 1);
    bin[0] = r0 * NT + t0; cw[0] = (1.0f - wr) * (1.0f - wt);
    bin[1] = r0 * NT + t1; cw[1] = (1.0f - wr) * wt;
    bin[2] = r1 * NT + t0; cw[2] = wr * (1.0f - wt);
    bin[3] = r1 * NT + t1; cw[3] = wr * wt;
}

// ---------------------------------------------------------------------------
// Step-0 pair weights. One wave per (b,n).
// ---------------------------------------------------------------------------
__global__ __launch_bounds__(64) void k_pairs0(const float* __restrict__ p,
                                               const float* __restrict__ car_mask,
                                               float* __restrict__ w4,
                                               int* __restrict__ bin4) {
    int b = blockIdx.x >> 6, n = blockIdx.x & 63;
    int s = threadIdx.x;
    float dx = p[(b * NV + n) * 2 + 0], dy = p[(b * NV + n) * 2 + 1];
    float relx = p[(b * NV + s) * 2 + 0] - dx;
    float rely = p[(b * NV + s) * 2 + 1] - dy;
    float valid, win; int bin[4]; float cw[4];
    pair_geom(relx, rely, car_mask[b * NV + s], valid, win, bin, cw);
    float c = valid;
#pragma unroll
    for (int off = 32; off > 0; off >>= 1) c += __shfl_xor(c, off);
    float bw = valid * win / fmaxf(c, 1.0f);
    int base = (blockIdx.x * NV + s) * 4;
#pragma unroll
    for (int q = 0; q < 4; ++q) { w4[base + q] = bw * cw[q]; bin4[base + q] = bin[q]; }
}

// ---------------------------------------------------------------------------
// One-time K transpose: KT[chunk j][pair p].
// ---------------------------------------------------------------------------
__global__ __launch_bounds__(256) void k_trans(
        const float* __restrict__ Kv, const float* __restrict__ K1g,
        const float* __restrict__ K2g, float4* __restrict__ KTv,
        float4* __restrict__ KT1, float4* __restrict__ KT2) {
    int idx = blockIdx.x * 256 + threadIdx.x;
    if (idx < 48 * 384) {
        int j = idx / 384, p = idx % 384;
        KTv[idx] = *(const float4*)(Kv + p * 192 + j * 4);
    } else if (idx < 48 * 384 + 16 * 384) {
        int r = idx - 48 * 384;
        int j = r / 384, p = r % 384;
        KT1[r] = *(const float4*)(K1g + p * 64 + j * 4);
    } else if (idx < 48 * 384 + 16 * 384 + 16 * 144) {
        int r = idx - (48 * 384 + 16 * 384);
        int j = r / 144, p = r % 144;
        KT2[r] = *(const float4*)(K2g + p * 64 + j * 4);
    }
}

// ---------------------------------------------------------------------------
// k_H0: per-source vehicle-layer H at t=0.
// ---------------------------------------------------------------------------
__global__ __launch_bounds__(256) void k_H0(const float* __restrict__ inb,
        const float4* __restrict__ KT, float* __restrict__ H) {
    __shared__ __align__(16) float s_f[192];
    int bs = blockIdx.x, tid = threadIdx.x;
    if (tid < 192) s_f[tid] = inb[bs * 192 + tid];
    __syncthreads();
    for (int p = tid; p < 384; p += 256) {
        float acc[KR];
#pragma unroll
        for (int m = 0; m < KR; ++m) acc[m] = 0.f;
#pragma unroll 8
        for (int i = 0; i < 24; ++i) {
            float4 k0 = KT[(2 * i) * 384 + p];
            float4 k1 = KT[(2 * i + 1) * 384 + p];
            float kk[8] = {k0.x, k0.y, k0.z, k0.w, k1.x, k1.y, k1.z, k1.w};
            float ff[8];
            *(float4*)&ff[0] = *(const float4*)&s_f[i * 8];
            *(float4*)&ff[4] = *(const float4*)&s_f[i * 8 + 4];
#pragma unroll
            for (int l = 0; l < KR; ++l) {
                float kl = kk[l];
#pragma unroll
                for (int m = 0; m < KR; ++m)
                    acc[m] = fmaf(kl, ff[(m - l) & 7], acc[m]);
            }
        }
        int rt = p >> 3, o = p & 7;
        float* hr = H + (size_t)(bs * RTOT + rt) * 64 + o * KR;
#pragma unroll
        for (int m = 0; m < KR; ++m) hr[m] = acc[m];
    }
}

// ---------------------------------------------------------------------------
// k_advHv: outputs[t-1], position update, pair weights, single-pass map
// encoder, back gate, feat write, fused own-row vehicle-layer H.
// ---------------------------------------------------------------------------
__global__ __launch_bounds__(256) void k_advHv(int t,
        const float* __restrict__ pprev, float* __restrict__ pcur,
        const float* __restrict__ outD, float* __restrict__ feat,
        const float* __restrict__ w_rho1, const float* __restrict__ WdBack,
        const float* __restrict__ Kmap, const float* __restrict__ map_p,
        const float* __restrict__ map_feat, const float* __restrict__ map_mask,
        const float* __restrict__ car_mask,
        float* __restrict__ w4, int* __restrict__ bin4,
        float* __restrict__ out,
        const float4* __restrict__ KTv, float* __restrict__ Hv) {
    __shared__ float s_out0[NV * KR];
    __shared__ float s_own[3 * KR];
    __shared__ float s_psrc[NV * 2];
    __shared__ float s_G4[4 * 96];
    __shared__ float s_G[96];
    __shared__ float s_wred[4];
    __shared__ float s_w2[KR * 2];
    __shared__ __align__(16) float s_f2[192];

    int tid = threadIdx.x;
    int bn = blockIdx.x, b = bn >> 6, n = bn & 63;

    for (int i = tid; i < NV * KR; i += 256)
        s_out0[i] = outD[(b * NV + (i >> 3)) * 24 + (i & 7)];
    if (tid < 24) s_own[tid] = outD[(b * NV + n) * 24 + tid];
    if (tid >= 32 && tid < 48) {
        int r = tid - 32, m = r >> 1, dd = r & 1;
        float ang = TWO_PIF * (float)m / (float)KR;
        float sn, cs; sincosf(ang, &sn, &cs);
        float w0 = w_rho1[0], wq = w_rho1[1];
        s_w2[r] = (dd == 0) ? (w0 * cs - wq * sn) : (w0 * sn + wq * cs);
    }
    if (tid < 96) { s_G4[tid] = 0.f; s_G4[96 + tid] = 0.f; s_G4[192 + tid] = 0.f; s_G4[288 + tid] = 0.f; }
    __syncthreads();

    if (tid < NV) {
        int s = tid;
        float dx0 = 0.0f, dy0 = 0.0f;
#pragma unroll
        for (int m = 0; m < KR; ++m) {
            float v = s_out0[s * KR + m];
            dx0 = fmaf(v, s_w2[m * 2 + 0], dx0);
            dy0 = fmaf(v, s_w2[m * 2 + 1], dy0);
        }
        s_psrc[s * 2 + 0] = pprev[(b * NV + s) * 2 + 0] + dx0;
        s_psrc[s * 2 + 1] = pprev[(b * NV + s) * 2 + 1] + dy0;
    }
    if (tid >= 64 && tid < 70) {
        int r = tid - 64, c = r >> 1, dd = r & 1;
        float acc = 0.0f;
#pragma unroll
        for (int m = 0; m < KR; ++m)
            acc = fmaf(s_own[c * KR + m], s_w2[m * 2 + dd], acc);
        if (c == 0) acc += pprev[(b * NV + n) * 2 + dd];
        out[(((t - 1) * NB + b) * NV + n) * 6 + c * 2 + dd] = acc;
    }
    __syncthreads();
    if (tid < 2) pcur[(b * NV + n) * 2 + tid] = s_psrc[n * 2 + tid];

    float pdx = s_psrc[n * 2 + 0], pdy = s_psrc[n * 2 + 1];

    if (tid < NV) {
        int s = tid;
        float valid, win; int bin[4]; float cw[4];
        pair_geom(s_psrc[s * 2 + 0] - pdx, s_psrc[s * 2 + 1] - pdy,
                  car_mask[b * NV + s], valid, win, bin, cw);
        float c = valid;
#pragma unroll
        for (int off = 32; off > 0; off >>= 1) c += __shfl_xor(c, off);
        float bw = valid * win / fmaxf(c, 1.0f);
        int base = (bn * NV + s) * 4;
#pragma unroll
        for (int q = 0; q < 4; ++q) { w4[base + q] = bw * cw[q]; bin4[base + q] = bin[q]; }
    }

    float lc = 0.0f;
    float* myG = &s_G4[(tid >> 6) * 96];
#pragma unroll
    for (int j = 0; j < NM / 256; ++j) {
        int s = tid + j * 256;
        float2 mp = *(const float2*)&map_p[(b * NM + s) * 2];
        float valid, win; int bin[4]; float cw[4];
        pair_geom(mp.x - pdx, mp.y - pdy, map_mask[b * NM + s], valid, win, bin, cw);
        lc += valid;
        float ww = valid * win;
        if (ww > 0.0f) {
            float2 f2 = *(const float2*)&map_feat[(b * NM + s) * 2];
#pragma unroll
            for (int q = 0; q < 4; ++q) {
                float w = ww * cw[q];
                atomicAdd(&myG[bin[q] * 2 + 0], w * f2.x);
                atomicAdd(&myG[bin[q] * 2 + 1], w * f2.y);
            }
        }
    }
#pragma unroll
    for (int off = 32; off > 0; off >>= 1) lc += __shfl_xor(lc, off);
    if ((tid & 63) == 0) s_wred[tid >> 6] = lc;
    __syncthreads();
    if (tid < 96) s_G[tid] = s_G4[tid] + s_G4[96 + tid] + s_G4[192 + tid] + s_G4[288 + tid];
    __syncthreads();
    float invc = 1.0f / fmaxf(s_wred[0] + s_wred[1] + s_wred[2] + s_wred[3], 1.0f);

    if (tid < 64) {
        float acc = 0.0f;
#pragma unroll 8
        for (int rt = 0; rt < RTOT; ++rt) {
            float2 k2 = *(const float2*)&Kmap[(rt * 64 + tid) * 2];
            acc = fmaf(k2.x, s_G[rt * 2 + 0], acc);
            acc = fmaf(k2.y, s_G[rt * 2 + 1], acc);
        }
        s_f2[128 + tid] = fmaxf(acc * invc, 0.0f);
    }
    if (tid >= 128) {
        int r = tid - 128, i = r >> 3, m = r & 7;
        float acc = 0.0f;
#pragma unroll
        for (int c = 0; c < 3; ++c)
#pragma unroll
            for (int l = 0; l < KR; ++l)
                acc = fmaf(WdBack[(i * 3 + c) * 8 + l], s_own[c * 8 + ((m - l) & 7)], acc);
        s_f2[r] = feat[(b * NV + n) * 192 + r] * tanhf(acc);
    }
    __syncthreads();
    if (tid < 192) feat[bn * 192 + tid] = s_f2[tid];

    for (int p = tid; p < 384; p += 256) {
        float acc[KR];
#pragma unroll
        for (int m = 0; m < KR; ++m) acc[m] = 0.f;
#pragma unroll 8
        for (int i = 0; i < 24; ++i) {
            float4 k0 = KTv[(2 * i) * 384 + p];
            float4 k1 = KTv[(2 * i + 1) * 384 + p];
            float kk[8] = {k0.x, k0.y, k0.z, k0.w, k1.x, k1.y, k1.z, k1.w};
            float ff[8];
            *(float4*)&ff[0] = *(const float4*)&s_f2[i * 8];
            *(float4*)&ff[4] = *(const float4*)&s_f2[i * 8 + 4];
#pragma unroll
            for (int l = 0; l < KR; ++l) {
                float kl = kk[l];
#pragma unroll
                for (int m = 0; m < KR; ++m)
                    acc[m] = fmaf(kl, ff[(m - l) & 7], acc[m]);
            }
        }
        int rt = p >> 3, o = p & 7;
        float* hr = Hv + (size_t)(bn * RTOT + rt) * 64 + o * KR;
#pragma unroll
        for (int m = 0; m < KR; ++m) hr[m] = acc[m];
    }
}

// ---------------------------------------------------------------------------
// k_aggH: [aggregate layer L (float4 row reads) + equilinear] -> out;
// then H for layer L+1 from relu(out).  HS = 64.
// Phase 1: 16-lane groups read whole H rows as float4; 4 entries in flight
// per wave; fully unrolled -> ~1-2 exposed latency rounds instead of ~8.
// ---------------------------------------------------------------------------
template<int ICH, bool RELU_IN, bool RESID, int OCH2>
__global__ __launch_bounds__(256) void k_aggH(const float* __restrict__ inb,
        const float* __restrict__ H, const float* __restrict__ Wd,
        const float* __restrict__ w4, const int* __restrict__ bin4,
        const float4* __restrict__ KT2, float* __restrict__ outb,
        float* __restrict__ Hout) {
    constexpr int NC = ICH * KR;
    constexpr int HS = 64;
    constexpr int NPAIR2 = RTOT * OCH2;
    constexpr int HS2 = OCH2 * KR;
    __shared__ float s_w[256];
    __shared__ int   s_row[256];
    __shared__ float s_in[NC];
    __shared__ __align__(16) float s_part[16 * HS];
    __shared__ __align__(16) float s_f2[HS];
    int tid = threadIdx.x, bn = blockIdx.x, b = bn >> 6;
    s_w[tid] = w4[bn * 256 + tid];
    s_row[tid] = (b * NV + (tid >> 2)) * RTOT + bin4[bn * 256 + tid];
    if (tid < NC) s_in[tid] = inb[bn * NC + tid];
    __syncthreads();
    // ---- phase 1: aggregation, float4 row reads
    {
        int w = tid >> 6, lane = tid & 63;
        int g = lane >> 4, c4 = lane & 15;
        float4 acc = make_float4(0.f, 0.f, 0.f, 0.f);
#pragma unroll
        for (int j = 0; j < 16; ++j) {
            int idx = w * 64 + j * 4 + g;
            float we = s_w[idx];
            float4 v = *(const float4*)&H[(size_t)s_row[idx] * HS + c4 * 4];
            acc.x = fmaf(we, v.x, acc.x);
            acc.y = fmaf(we, v.y, acc.y);
            acc.z = fmaf(we, v.z, acc.z);
            acc.w = fmaf(we, v.w, acc.w);
        }
        *(float4*)&s_part[(w * 4 + g) * HS + c4 * 4] = acc;
    }
    __syncthreads();
    if (tid < HS) {
        float tot = 0.f;
#pragma unroll
        for (int k = 0; k < 16; ++k) tot += s_part[k * HS + tid];
        int o = tid / KR, m = tid & 7;
#pragma unroll
        for (int i = 0; i < ICH; ++i) {
            const float* Wr = Wd + (o * ICH + i) * KR;
#pragma unroll
            for (int l = 0; l < KR; ++l) {
                float v = s_in[i * KR + ((m - l) & 7)];
                if (RELU_IN) v = fmaxf(v, 0.f);
                tot = fmaf(Wr[l], v, tot);
            }
        }
        if (RESID) tot += s_in[tid];
        outb[bn * HS + tid] = tot;
        s_f2[tid] = fmaxf(tot, 0.f);
    }
    __syncthreads();
    // ---- phase 2: H for next layer (ICH2 = 8)
    for (int p = tid; p < NPAIR2; p += 256) {
        float acc2[KR];
#pragma unroll
        for (int m = 0; m < KR; ++m) acc2[m] = 0.f;
#pragma unroll 4
        for (int i = 0; i < 8; ++i) {
            float4 k0 = KT2[(2 * i) * NPAIR2 + p];
            float4 k1 = KT2[(2 * i + 1) * NPAIR2 + p];
            float kk[8] = {k0.x, k0.y, k0.z, k0.w, k1.x, k1.y, k1.z, k1.w};
            float ff[8];
            *(float4*)&ff[0] = *(const float4*)&s_f2[i * 8];
            *(float4*)&ff[4] = *(const float4*)&s_f2[i * 8 + 4];
#pragma unroll
            for (int l = 0; l < KR; ++l) {
                float kl = kk[l];
#pragma unroll
                for (int m = 0; m < KR; ++m)
                    acc2[m] = fmaf(kl, ff[(m - l) & 7], acc2[m]);
            }
        }
        int rt = p / OCH2, o = p - rt * OCH2;
        float* hr = Hout + (size_t)(bn * RTOT + rt) * HS2 + o * KR;
#pragma unroll
        for (int m = 0; m < KR; ++m) hr[m] = acc2[m];
    }
}

// ---------------------------------------------------------------------------
// k_agg3: last layer (HS = 24), float4 row reads (6 quads per row,
// 8 entries in flight per wave), + equilinear + relu.
// ---------------------------------------------------------------------------
__global__ __launch_bounds__(256) void k_agg3(const float* __restrict__ inb,
        const float* __restrict__ H, const float* __restrict__ Wd,
        const float* __restrict__ w4, const int* __restrict__ bin4,
        float* __restrict__ outb) {
    constexpr int NC = 64;               // ICH = 8
    constexpr int HS = 24;               // OCH = 3
    __shared__ float s_w[256];
    __shared__ int   s_row[256];
    __shared__ float s_in[NC];
    __shared__ __align__(16) float s_part[32 * HS];
    int tid = threadIdx.x, bn = blockIdx.x, b = bn >> 6;
    s_w[tid] = w4[bn * 256 + tid];
    s_row[tid] = (b * NV + (tid >> 2)) * RTOT + bin4[bn * 256 + tid];
    if (tid < NC) s_in[tid] = inb[bn * NC + tid];
    __syncthreads();
    {
        int w = tid >> 6, lane = tid & 63;
        int g = lane >> 3, c4 = lane & 7;        // 8 entries in flight; quads 0..5 live
        float4 acc = make_float4(0.f, 0.f, 0.f, 0.f);
#pragma unroll
        for (int j = 0; j < 8; ++j) {
            int idx = w * 64 + j * 8 + g;
            float we = s_w[idx];
            if (c4 < 6) {
                float4 v = *(const float4*)&H[(size_t)s_row[idx] * HS + c4 * 4];
                acc.x = fmaf(we, v.x, acc.x);
                acc.y = fmaf(we, v.y, acc.y);
                acc.z = fmaf(we, v.z, acc.z);
                acc.w = fmaf(we, v.w, acc.w);
            }
        }
        if (c4 < 6) *(float4*)&s_part[(w * 8 + g) * HS + c4 * 4] = acc;
    }
    __syncthreads();
    if (tid < HS) {
        float tot = 0.f;
#pragma unroll
        for (int k = 0; k < 32; ++k) tot += s_part[k * HS + tid];
        int o = tid / KR, m = tid & 7;
#pragma unroll
        for (int i = 0; i < 8; ++i) {
            const float* Wr = Wd + (o * 8 + i) * KR;
#pragma unroll
            for (int l = 0; l < KR; ++l)
                tot = fmaf(Wr[l], fmaxf(s_in[i * KR + ((m - l) & 7)], 0.f), tot);
        }
        outb[bn * HS + tid] = fmaxf(tot, 0.f);
    }
}

// ---------------------------------------------------------------------------
// Final write: outputs[29]
// ---------------------------------------------------------------------------
__global__ void k_final(const float* __restrict__ outD, const float* __restrict__ pcur,
                        const float* __restrict__ w_rho1, float* __restrict__ out) {
    int idx = blockIdx.x * blockDim.x + threadIdx.x;
    if (idx >= NB * NV * 6) return;
    int bn = idx / 6, r = idx % 6, c = r >> 1, dd = r & 1;
    float w0 = w_rho1[0], wq = w_rho1[1];
    float acc = 0.0f;
#pragma unroll
    for (int m = 0; m < KR; ++m) {
        float ang = TWO_PIF * (float)m / (float)KR;
        float sn, cs; sincosf(ang, &sn, &cs);
        float w2 = (dd == 0) ? (w0 * cs - wq * sn) : (w0 * sn + wq * cs);
        acc = fmaf(outD[bn * 24 + c * 8 + m], w2, acc);
    }
    if (c == 0) acc += pcur[bn * 2 + dd];
    out[(29 * NB * NV + bn) * 6 + r] = acc;
}

// ---------------------------------------------------------------------------
extern "C" void kernel_launch(void* const* d_in, const int* in_sizes, int n_in,
                              void* d_out, int out_size, void* d_ws, size_t ws_size,
                              hipStream_t stream) {
    const float* in_p     = (const float*)d_in[0];
    const float* in_feat  = (const float*)d_in[1];
    const float* map_p    = (const float*)d_in[2];
    const float* map_feat = (const float*)d_in[3];
    const float* car_mask = (const float*)d_in[4];
    const float* map_mask = (const float*)d_in[5];
    const float* Kv       = (const float*)d_in[6];
    const float* WdV      = (const float*)d_in[7];
    const float* K1       = (const float*)d_in[8];
    const float* Wd1      = (const float*)d_in[9];
    const float* K2       = (const float*)d_in[10];
    const float* Wd2      = (const float*)d_in[11];
    const float* WdBack   = (const float*)d_in[12];
    const float* w_rho1   = (const float*)d_in[13];
    const float* Kmap     = (const float*)d_in[14];

    float* ws   = (float*)d_ws;
    float* pbuf0 = ws;                       // 1024
    float* pbuf1 = ws + 1024;                // 1024
    float* feat  = ws + 2048;                // 98304  [512][192]
    float* out1  = ws + 100352;              // 32768
    float* out2  = ws + 133120;              // 32768
    float* outD  = ws + 165888;              // 12288  [512][24]
    float* w4    = ws + 178176;              // 131072
    int*   bin4  = (int*)(ws + 309248);      // 131072 ints
    float4* KTv  = (float4*)(ws + 440320);   // 73728 floats
    float4* KT1  = (float4*)(ws + 514048);   // 24576 floats
    float4* KT2  = (float4*)(ws + 538624);   // 9216 floats
    float* Hv    = ws + 547840;              // 1572864 [512][48][64]
    float* H1    = ws + 2120704;             // 1572864
    float* H2    = ws + 3693568;             // 589824  [512][48][24]
    float* out   = (float*)d_out;

    hipMemcpyAsync(pbuf0, in_p, NB * NV * 2 * sizeof(float),
                   hipMemcpyDeviceToDevice, stream);
    hipMemcpyAsync(feat, in_feat, NB * NV * 24 * KR * sizeof(float),
                   hipMemcpyDeviceToDevice, stream);

    k_trans<<<105, 256, 0, stream>>>(Kv, K1, K2, KTv, KT1, KT2);
    k_pairs0<<<NB * NV, 64, 0, stream>>>(pbuf0, car_mask, w4, bin4);

    auto decode = [&]() {
        k_aggH<24, false, false, 8><<<NB * NV, 256, 0, stream>>>(feat, Hv, WdV, w4, bin4, KT1, out1, H1);
        k_aggH<8, true, true, 3><<<NB * NV, 256, 0, stream>>>(out1, H1, Wd1, w4, bin4, KT2, out2, H2);
        k_agg3<<<NB * NV, 256, 0, stream>>>(out2, H2, Wd2, w4, bin4, outD);
    };

    k_H0<<<NB * NV, 256, 0, stream>>>(feat, KTv, Hv);
    decode();
    for (int t = 1; t < 30; ++t) {
        float* pprev = (t & 1) ? pbuf0 : pbuf1;
        float* pcur  = (t & 1) ? pbuf1 : pbuf0;
        k_advHv<<<NB * NV, 256, 0, stream>>>(t, pprev, pcur, outD, feat,
                                             w_rho1, WdBack, Kmap, map_p, map_feat,
                                             map_mask, car_mask, w4, bin4, out,
                                             KTv, Hv);
        decode();
    }
    k_final<<<12, 256, 0, stream>>>(outD, pbuf1, w_rho1, out);
}

// Round 11
// 1743.659 us; speedup vs baseline: 8.2842x; 1.0121x over previous
//
#include <hip/hip_runtime.h>
#include <math.h>

#define NB 8
#define NV 64
#define NM 1024
#define NR 3
#define NT 16
#define KR 8
#define RTOT 48                 // NR*NT
#define RADIUSF 40.0f
#define TWO_PIF 6.283185307179586f

// ---------------------------------------------------------------------------
// Pair geometry: replicates the reference bilinear polar binning exactly.
// ---------------------------------------------------------------------------
__device__ __forceinline__ void pair_geom(float relx, float rely, float mask,
                                          float& valid, float& win,
                                          int bin[4], float cw[4]) {
    float d = sqrtf(relx * relx + rely * rely + 1e-12f);
    valid = (d < RADIUSF) ? mask : 0.0f;
    float q = d * (1.0f / RADIUSF);
    float w1 = fmaxf(1.0f - q * q, 0.0f);
    win = w1 * w1 * w1;
    float u = fminf(fmaxf(q, 0.0f), 1.0f) * (float)(NR - 1);
    float r0f = floorf(u);
    float wr = u - r0f;
    int r0 = (int)r0f;
    int r1 = min(r0 + 1, NR - 1);
    float a = atan2f(rely, relx) * (1.0f / TWO_PIF);
    a = a - floorf(a);                  // mod 1 -> [0,1)
    float t = a * (float)NT;
    float t0f = floorf(t);
    float wt = t - t0f;
    int t0 = ((int)t0f) & (NT - 1);
    int t1 = (t0 + 1) & (NT - 1);
    bin[0] = r0 * NT + t0; cw[0] = (1.0f - wr) * (1.0f - wt);
    bin[1] = r0 * NT + t1; cw[1] = (1.0f - wr) * wt;
    bin[2] = r1 * NT + t0; cw[2] = wr * (1.0f - wt);
    bin[3] = r1 * NT + t1; cw[3] = wr * wt;
}

// ---------------------------------------------------------------------------
// One-time K transpose: KT[chunk j][pair p].
// ---------------------------------------------------------------------------
__global__ __launch_bounds__(256) void k_trans(
        const float* __restrict__ Kv, const float* __restrict__ K1g,
        const float* __restrict__ K2g, float4* __restrict__ KTv,
        float4* __restrict__ KT1, float4* __restrict__ KT2) {
    int idx = blockIdx.x * 256 + threadIdx.x;
    if (idx < 48 * 384) {
        int j = idx / 384, p = idx % 384;
        KTv[idx] = *(const float4*)(Kv + p * 192 + j * 4);
    } else if (idx < 48 * 384 + 16 * 384) {
        int r = idx - 48 * 384;
        int j = r / 384, p = r % 384;
        KT1[r] = *(const float4*)(K1g + p * 64 + j * 4);
    } else if (idx < 48 * 384 + 16 * 384 + 16 * 144) {
        int r = idx - (48 * 384 + 16 * 384);
        int j = r / 144, p = r % 144;
        KT2[r] = *(const float4*)(K2g + p * 64 + j * 4);
    }
}

// ---------------------------------------------------------------------------
// k_H0: per-source vehicle-layer H at t=0 (feat = initial features).
// ---------------------------------------------------------------------------
__global__ __launch_bounds__(256) void k_H0(const float* __restrict__ inb,
        const float4* __restrict__ KT, float* __restrict__ H) {
    __shared__ __align__(16) float s_f[192];
    int bs = blockIdx.x, tid = threadIdx.x;
    if (tid < 192) s_f[tid] = inb[bs * 192 + tid];
    __syncthreads();
    for (int p = tid; p < 384; p += 256) {
        float acc[KR];
#pragma unroll
        for (int m = 0; m < KR; ++m) acc[m] = 0.f;
#pragma unroll 8
        for (int i = 0; i < 24; ++i) {
            float4 k0 = KT[(2 * i) * 384 + p];
            float4 k1 = KT[(2 * i + 1) * 384 + p];
            float kk[8] = {k0.x, k0.y, k0.z, k0.w, k1.x, k1.y, k1.z, k1.w};
            float ff[8];
            *(float4*)&ff[0] = *(const float4*)&s_f[i * 8];
            *(float4*)&ff[4] = *(const float4*)&s_f[i * 8 + 4];
#pragma unroll
            for (int l = 0; l < KR; ++l) {
                float kl = kk[l];
#pragma unroll
                for (int m = 0; m < KR; ++m)
                    acc[m] = fmaf(kl, ff[(m - l) & 7], acc[m]);
            }
        }
        int rt = p >> 3, o = p & 7;
        float* hr = H + (size_t)(bs * RTOT + rt) * 64 + o * KR;
#pragma unroll
        for (int m = 0; m < KR; ++m) hr[m] = acc[m];
    }
}

// ---------------------------------------------------------------------------
// k_A (t = 1..29): closes step t-1 and opens step t for ONE vehicle bn.
//   phase 1: aggregate H2 + equilinear(Wd2, relu(out2)) -> relu -> s_oD (LDS only)
//   phase 2: outputs[t-1] = reg2rho1(s_oD) (+ p_{t-1} ch0); p_t = p_{t-1}+delta
//   phase 3: map encoder at p_t (single pass, per-wave LDS atomics)
//   phase 4: back gate + enc -> s_f2; feat write
//   phase 5: Hv_t = KTv circ-conv s_f2
// Pair weights are NOT computed here (k_B head does, from updated p).
// ---------------------------------------------------------------------------
__global__ __launch_bounds__(256) void k_A(int t,
        float* __restrict__ p, const float* __restrict__ out2buf,
        const float* __restrict__ H2, const float* __restrict__ Wd2,
        const float* __restrict__ w4, const int* __restrict__ bin4,
        float* __restrict__ feat,
        const float* __restrict__ w_rho1, const float* __restrict__ WdBack,
        const float* __restrict__ Kmap, const float* __restrict__ map_p,
        const float* __restrict__ map_feat, const float* __restrict__ map_mask,
        const float4* __restrict__ KTv, float* __restrict__ Hv,
        float* __restrict__ out) {
    __shared__ float s_w[256];
    __shared__ int   s_row[256];
    __shared__ float s_in[64];
    __shared__ __align__(16) float s_part[32 * 24];
    __shared__ float s_oD[24];
    __shared__ float s_w2[16];
    __shared__ float s_G4[4 * 96];
    __shared__ float s_G[96];
    __shared__ float s_wred[4];
    __shared__ __align__(16) float s_f2[192];

    int tid = threadIdx.x, bn = blockIdx.x, b = bn >> 6, n = bn & 63;
    float2 pold = *(const float2*)&p[bn * 2];     // read BEFORE update

    s_w[tid] = w4[bn * 256 + tid];
    s_row[tid] = (b * NV + (tid >> 2)) * RTOT + bin4[bn * 256 + tid];
    if (tid < 64) s_in[tid] = out2buf[bn * 64 + tid];
    if (tid >= 224 && tid < 240) {
        int r = tid - 224, m = r >> 1, dd = r & 1;
        float ang = TWO_PIF * (float)m / (float)KR;
        float sn, cs; sincosf(ang, &sn, &cs);
        float w0 = w_rho1[0], wq = w_rho1[1];
        s_w2[r] = (dd == 0) ? (w0 * cs - wq * sn) : (w0 * sn + wq * cs);
    }
    if (tid < 96) { s_G4[tid] = 0.f; s_G4[96 + tid] = 0.f; s_G4[192 + tid] = 0.f; s_G4[288 + tid] = 0.f; }
    __syncthreads();

    // ---- phase 1: aggregate H2 (HS=24), float4 row reads
    {
        int w = tid >> 6, lane = tid & 63;
        int g = lane >> 3, c4 = lane & 7;
        float4 acc = make_float4(0.f, 0.f, 0.f, 0.f);
#pragma unroll
        for (int j = 0; j < 8; ++j) {
            int idx = w * 64 + j * 8 + g;
            float we = s_w[idx];
            if (c4 < 6) {
                float4 v = *(const float4*)&H2[(size_t)s_row[idx] * 24 + c4 * 4];
                acc.x = fmaf(we, v.x, acc.x);
                acc.y = fmaf(we, v.y, acc.y);
                acc.z = fmaf(we, v.z, acc.z);
                acc.w = fmaf(we, v.w, acc.w);
            }
        }
        if (c4 < 6) *(float4*)&s_part[(w * 8 + g) * 24 + c4 * 4] = acc;
    }
    __syncthreads();
    if (tid < 24) {
        float tot = 0.f;
#pragma unroll
        for (int k = 0; k < 32; ++k) tot += s_part[k * 24 + tid];
        int o = tid / KR, m = tid & 7;
#pragma unroll
        for (int i = 0; i < 8; ++i) {
            const float* Wr = Wd2 + (o * 8 + i) * KR;
#pragma unroll
            for (int l = 0; l < KR; ++l)
                tot = fmaf(Wr[l], fmaxf(s_in[i * KR + ((m - l) & 7)], 0.f), tot);
        }
        s_oD[tid] = fmaxf(tot, 0.f);
    }
    __syncthreads();

    // ---- phase 2: outputs[t-1] + own position update
    float dx0 = 0.f, dy0 = 0.f;
#pragma unroll
    for (int m = 0; m < KR; ++m) {
        float v = s_oD[m];
        dx0 = fmaf(v, s_w2[m * 2 + 0], dx0);
        dy0 = fmaf(v, s_w2[m * 2 + 1], dy0);
    }
    if (tid < 6) {
        int c = tid >> 1, dd = tid & 1;
        float acc = 0.f;
#pragma unroll
        for (int m = 0; m < KR; ++m)
            acc = fmaf(s_oD[c * KR + m], s_w2[m * 2 + dd], acc);
        if (c == 0) acc += (dd ? pold.y : pold.x);
        out[(((t - 1) * NB + b) * NV + n) * 6 + tid] = acc;
    }
    float pdx = pold.x + dx0, pdy = pold.y + dy0;
    if (tid == 0) { p[bn * 2 + 0] = pdx; p[bn * 2 + 1] = pdy; }

    // ---- phase 3: map encoder single pass at p_t
    float lc = 0.f;
    float* myG = &s_G4[(tid >> 6) * 96];
#pragma unroll
    for (int j = 0; j < NM / 256; ++j) {
        int s = tid + j * 256;
        float2 mp = *(const float2*)&map_p[(b * NM + s) * 2];
        float valid, win; int bin[4]; float cw[4];
        pair_geom(mp.x - pdx, mp.y - pdy, map_mask[b * NM + s], valid, win, bin, cw);
        lc += valid;
        float ww = valid * win;
        if (ww > 0.f) {
            float2 f2 = *(const float2*)&map_feat[(b * NM + s) * 2];
#pragma unroll
            for (int q = 0; q < 4; ++q) {
                float w = ww * cw[q];
                atomicAdd(&myG[bin[q] * 2 + 0], w * f2.x);
                atomicAdd(&myG[bin[q] * 2 + 1], w * f2.y);
            }
        }
    }
#pragma unroll
    for (int off = 32; off > 0; off >>= 1) lc += __shfl_xor(lc, off);
    if ((tid & 63) == 0) s_wred[tid >> 6] = lc;
    __syncthreads();
    if (tid < 96) s_G[tid] = s_G4[tid] + s_G4[96 + tid] + s_G4[192 + tid] + s_G4[288 + tid];
    __syncthreads();
    float invc = 1.0f / fmaxf(s_wred[0] + s_wred[1] + s_wred[2] + s_wred[3], 1.0f);

    // ---- phase 4: enc + back gate -> s_f2; feat write
    if (tid < 64) {
        float acc = 0.f;
#pragma unroll 8
        for (int rt = 0; rt < RTOT; ++rt) {
            float2 k2 = *(const float2*)&Kmap[(rt * 64 + tid) * 2];
            acc = fmaf(k2.x, s_G[rt * 2 + 0], acc);
            acc = fmaf(k2.y, s_G[rt * 2 + 1], acc);
        }
        s_f2[128 + tid] = fmaxf(acc * invc, 0.f);
    }
    if (tid >= 128) {
        int r = tid - 128, i = r >> 3, m = r & 7;
        float acc = 0.f;
#pragma unroll
        for (int c = 0; c < 3; ++c)
#pragma unroll
            for (int l = 0; l < KR; ++l)
                acc = fmaf(WdBack[(i * 3 + c) * 8 + l], s_oD[c * 8 + ((m - l) & 7)], acc);
        s_f2[r] = feat[bn * 192 + r] * tanhf(acc);
    }
    __syncthreads();
    if (tid < 192) feat[bn * 192 + tid] = s_f2[tid];

    // ---- phase 5: Hv from s_f2
    for (int pp = tid; pp < 384; pp += 256) {
        float acc[KR];
#pragma unroll
        for (int m = 0; m < KR; ++m) acc[m] = 0.f;
#pragma unroll 8
        for (int i = 0; i < 24; ++i) {
            float4 k0 = KTv[(2 * i) * 384 + pp];
            float4 k1 = KTv[(2 * i + 1) * 384 + pp];
            float kk[8] = {k0.x, k0.y, k0.z, k0.w, k1.x, k1.y, k1.z, k1.w};
            float ff[8];
            *(float4*)&ff[0] = *(const float4*)&s_f2[i * 8];
            *(float4*)&ff[4] = *(const float4*)&s_f2[i * 8 + 4];
#pragma unroll
            for (int l = 0; l < KR; ++l) {
                float kl = kk[l];
#pragma unroll
                for (int m = 0; m < KR; ++m)
                    acc[m] = fmaf(kl, ff[(m - l) & 7], acc[m]);
            }
        }
        int rt = pp >> 3, o = pp & 7;
        float* hr = Hv + (size_t)(bn * RTOT + rt) * 64 + o * KR;
#pragma unroll
        for (int m = 0; m < KR; ++m) hr[m] = acc[m];
    }
}

// ---------------------------------------------------------------------------
// k_B: head computes pair weights from updated p (writes w4/bin4 for k_C and
// next k_A); then layer-1 aggregation (float4 rows) + equilinear(WdV, feat)
// -> out1; then H1 from relu(out1).
// ---------------------------------------------------------------------------
__global__ __launch_bounds__(256) void k_B(
        const float* __restrict__ p, const float* __restrict__ car_mask,
        const float* __restrict__ feat, const float* __restrict__ Hv,
        const float* __restrict__ WdV,
        float* __restrict__ w4, int* __restrict__ bin4,
        const float4* __restrict__ KT1,
        float* __restrict__ out1, float* __restrict__ H1) {
    __shared__ float s_psrc[NV * 2];
    __shared__ float s_w[256];
    __shared__ int   s_row[256];
    __shared__ __align__(16) float s_in[192];
    __shared__ __align__(16) float s_part[16 * 64];
    __shared__ __align__(16) float s_f2[64];
    int tid = threadIdx.x, bn = blockIdx.x, b = bn >> 6, n = bn & 63;
    if (tid < 128) s_psrc[tid] = p[b * 128 + tid];
    if (tid < 192) s_in[tid] = feat[bn * 192 + tid];
    __syncthreads();
    // ---- pair weights (wave 0)
    if (tid < NV) {
        int s = tid;
        float valid, win; int bin[4]; float cw[4];
        pair_geom(s_psrc[s * 2 + 0] - s_psrc[n * 2 + 0],
                  s_psrc[s * 2 + 1] - s_psrc[n * 2 + 1],
                  car_mask[b * NV + s], valid, win, bin, cw);
        float c = valid;
#pragma unroll
        for (int off = 32; off > 0; off >>= 1) c += __shfl_xor(c, off);
        float bw = valid * win / fmaxf(c, 1.0f);
#pragma unroll
        for (int q = 0; q < 4; ++q) {
            float wv = bw * cw[q];
            s_w[s * 4 + q] = wv;
            s_row[s * 4 + q] = (b * NV + s) * RTOT + bin[q];
            w4[bn * 256 + s * 4 + q] = wv;
            bin4[bn * 256 + s * 4 + q] = bin[q];
        }
    }
    __syncthreads();
    // ---- phase 1: aggregation over Hv (float4 rows) + equilinear
    {
        int w = tid >> 6, lane = tid & 63;
        int g = lane >> 4, c4 = lane & 15;
        float4 acc = make_float4(0.f, 0.f, 0.f, 0.f);
#pragma unroll
        for (int j = 0; j < 16; ++j) {
            int idx = w * 64 + j * 4 + g;
            float we = s_w[idx];
            float4 v = *(const float4*)&Hv[(size_t)s_row[idx] * 64 + c4 * 4];
            acc.x = fmaf(we, v.x, acc.x);
            acc.y = fmaf(we, v.y, acc.y);
            acc.z = fmaf(we, v.z, acc.z);
            acc.w = fmaf(we, v.w, acc.w);
        }
        *(float4*)&s_part[(w * 4 + g) * 64 + c4 * 4] = acc;
    }
    __syncthreads();
    if (tid < 64) {
        float tot = 0.f;
#pragma unroll
        for (int k = 0; k < 16; ++k) tot += s_part[k * 64 + tid];
        int o = tid >> 3, m = tid & 7;
#pragma unroll
        for (int i = 0; i < 24; ++i) {
            const float* Wr = WdV + (o * 24 + i) * KR;
#pragma unroll
            for (int l = 0; l < KR; ++l)
                tot = fmaf(Wr[l], s_in[i * KR + ((m - l) & 7)], tot);
        }
        out1[bn * 64 + tid] = tot;
        s_f2[tid] = fmaxf(tot, 0.f);
    }
    __syncthreads();
    // ---- phase 2: H1 from relu(out1)
    for (int pp = tid; pp < 384; pp += 256) {
        float acc2[KR];
#pragma unroll
        for (int m = 0; m < KR; ++m) acc2[m] = 0.f;
#pragma unroll 4
        for (int i = 0; i < 8; ++i) {
            float4 k0 = KT1[(2 * i) * 384 + pp];
            float4 k1 = KT1[(2 * i + 1) * 384 + pp];
            float kk[8] = {k0.x, k0.y, k0.z, k0.w, k1.x, k1.y, k1.z, k1.w};
            float ff[8];
            *(float4*)&ff[0] = *(const float4*)&s_f2[i * 8];
            *(float4*)&ff[4] = *(const float4*)&s_f2[i * 8 + 4];
#pragma unroll
            for (int l = 0; l < KR; ++l) {
                float kl = kk[l];
#pragma unroll
                for (int m = 0; m < KR; ++m)
                    acc2[m] = fmaf(kl, ff[(m - l) & 7], acc2[m]);
            }
        }
        int rt = pp >> 3, o = pp & 7;
        float* hr = H1 + (size_t)(bn * RTOT + rt) * 64 + o * KR;
#pragma unroll
        for (int m = 0; m < KR; ++m) hr[m] = acc2[m];
    }
}

// ---------------------------------------------------------------------------
// k_C: layer-2 aggregation (float4 rows) + equilinear(Wd1, relu(out1)) +
// residual -> out2; H2 from relu(out2).  (= proven k_aggH<8,true,true,3>)
// ---------------------------------------------------------------------------
__global__ __launch_bounds__(256) void k_C(const float* __restrict__ out1,
        const float* __restrict__ H1, const float* __restrict__ Wd1,
        const float* __restrict__ w4, const int* __restrict__ bin4,
        const float4* __restrict__ KT2, float* __restrict__ out2,
        float* __restrict__ H2) {
    __shared__ float s_w[256];
    __shared__ int   s_row[256];
    __shared__ float s_in[64];
    __shared__ __align__(16) float s_part[16 * 64];
    __shared__ __align__(16) float s_f2[64];
    int tid = threadIdx.x, bn = blockIdx.x, b = bn >> 6;
    s_w[tid] = w4[bn * 256 + tid];
    s_row[tid] = (b * NV + (tid >> 2)) * RTOT + bin4[bn * 256 + tid];
    if (tid < 64) s_in[tid] = out1[bn * 64 + tid];
    __syncthreads();
    {
        int w = tid >> 6, lane = tid & 63;
        int g = lane >> 4, c4 = lane & 15;
        float4 acc = make_float4(0.f, 0.f, 0.f, 0.f);
#pragma unroll
        for (int j = 0; j < 16; ++j) {
            int idx = w * 64 + j * 4 + g;
            float we = s_w[idx];
            float4 v = *(const float4*)&H1[(size_t)s_row[idx] * 64 + c4 * 4];
            acc.x = fmaf(we, v.x, acc.x);
            acc.y = fmaf(we, v.y, acc.y);
            acc.z = fmaf(we, v.z, acc.z);
            acc.w = fmaf(we, v.w, acc.w);
        }
        *(float4*)&s_part[(w * 4 + g) * 64 + c4 * 4] = acc;
    }
    __syncthreads();
    if (tid < 64) {
        float tot = 0.f;
#pragma unroll
        for (int k = 0; k < 16; ++k) tot += s_part[k * 64 + tid];
        int o = tid >> 3, m = tid & 7;
#pragma unroll
        for (int i = 0; i < 8; ++i) {
            const float* Wr = Wd1 + (o * 8 + i) * KR;
#pragma unroll
            for (int l = 0; l < KR; ++l)
                tot = fmaf(Wr[l], fmaxf(s_in[i * KR + ((m - l) & 7)], 0.f), tot);
        }
        tot += s_in[tid];
        out2[bn * 64 + tid] = tot;
        s_f2[tid] = fmaxf(tot, 0.f);
    }
    __syncthreads();
    for (int pp = tid; pp < 144; pp += 256) {
        float acc2[KR];
#pragma unroll
        for (int m = 0; m < KR; ++m) acc2[m] = 0.f;
#pragma unroll 4
        for (int i = 0; i < 8; ++i) {
            float4 k0 = KT2[(2 * i) * 144 + pp];
            float4 k1 = KT2[(2 * i + 1) * 144 + pp];
            float kk[8] = {k0.x, k0.y, k0.z, k0.w, k1.x, k1.y, k1.z, k1.w};
            float ff[8];
            *(float4*)&ff[0] = *(const float4*)&s_f2[i * 8];
            *(float4*)&ff[4] = *(const float4*)&s_f2[i * 8 + 4];
#pragma unroll
            for (int l = 0; l < KR; ++l) {
                float kl = kk[l];
#pragma unroll
                for (int m = 0; m < KR; ++m)
                    acc2[m] = fmaf(kl, ff[(m - l) & 7], acc2[m]);
            }
        }
        int rt = pp / 3, o = pp - rt * 3;
        float* hr = H2 + (size_t)(bn * RTOT + rt) * 24 + o * KR;
#pragma unroll
        for (int m = 0; m < KR; ++m) hr[m] = acc2[m];
    }
}

// ---------------------------------------------------------------------------
// k_fin: aggregate H2_29 -> outD_29; outputs[29] = reg2rho1 + p_29 (ch0).
// ---------------------------------------------------------------------------
__global__ __launch_bounds__(256) void k_fin(
        const float* __restrict__ p, const float* __restrict__ out2buf,
        const float* __restrict__ H2, const float* __restrict__ Wd2,
        const float* __restrict__ w4, const int* __restrict__ bin4,
        const float* __restrict__ w_rho1, float* __restrict__ out) {
    __shared__ float s_w[256];
    __shared__ int   s_row[256];
    __shared__ float s_in[64];
    __shared__ __align__(16) float s_part[32 * 24];
    __shared__ float s_oD[24];
    __shared__ float s_w2[16];
    int tid = threadIdx.x, bn = blockIdx.x, b = bn >> 6, n = bn & 63;
    s_w[tid] = w4[bn * 256 + tid];
    s_row[tid] = (b * NV + (tid >> 2)) * RTOT + bin4[bn * 256 + tid];
    if (tid < 64) s_in[tid] = out2buf[bn * 64 + tid];
    if (tid >= 224 && tid < 240) {
        int r = tid - 224, m = r >> 1, dd = r & 1;
        float ang = TWO_PIF * (float)m / (float)KR;
        float sn, cs; sincosf(ang, &sn, &cs);
        float w0 = w_rho1[0], wq = w_rho1[1];
        s_w2[r] = (dd == 0) ? (w0 * cs - wq * sn) : (w0 * sn + wq * cs);
    }
    __syncthreads();
    {
        int w = tid >> 6, lane = tid & 63;
        int g = lane >> 3, c4 = lane & 7;
        float4 acc = make_float4(0.f, 0.f, 0.f, 0.f);
#pragma unroll
        for (int j = 0; j < 8; ++j) {
            int idx = w * 64 + j * 8 + g;
            float we = s_w[idx];
            if (c4 < 6) {
                float4 v = *(const float4*)&H2[(size_t)s_row[idx] * 24 + c4 * 4];
                acc.x = fmaf(we, v.x, acc.x);
                acc.y = fmaf(we, v.y, acc.y);
                acc.z = fmaf(we, v.z, acc.z);
                acc.w = fmaf(we, v.w, acc.w);
            }
        }
        if (c4 < 6) *(float4*)&s_part[(w * 8 + g) * 24 + c4 * 4] = acc;
    }
    __syncthreads();
    if (tid < 24) {
        float tot = 0.f;
#pragma unroll
        for (int k = 0; k < 32; ++k) tot += s_part[k * 24 + tid];
        int o = tid / KR, m = tid & 7;
#pragma unroll
        for (int i = 0; i < 8; ++i) {
            const float* Wr = Wd2 + (o * 8 + i) * KR;
#pragma unroll
            for (int l = 0; l < KR; ++l)
                tot = fmaf(Wr[l], fmaxf(s_in[i * KR + ((m - l) & 7)], 0.f), tot);
        }
        s_oD[tid] = fmaxf(tot, 0.f);
    }
    __syncthreads();
    if (tid < 6) {
        int c = tid >> 1, dd = tid & 1;
        float acc = 0.f;
#pragma unroll
        for (int m = 0; m < KR; ++m)
            acc = fmaf(s_oD[c * KR + m], s_w2[m * 2 + dd], acc);
        if (c == 0) acc += p[bn * 2 + dd];
        out[((29 * NB + b) * NV + n) * 6 + tid] = acc;
    }
}

// ---------------------------------------------------------------------------
extern "C" void kernel_launch(void* const* d_in, const int* in_sizes, int n_in,
                              void* d_out, int out_size, void* d_ws, size_t ws_size,
                              hipStream_t stream) {
    const float* in_p     = (const float*)d_in[0];
    const float* in_feat  = (const float*)d_in[1];
    const float* map_p    = (const float*)d_in[2];
    const float* map_feat = (const float*)d_in[3];
    const float* car_mask = (const float*)d_in[4];
    const float* map_mask = (const float*)d_in[5];
    const float* Kv       = (const float*)d_in[6];
    const float* WdV      = (const float*)d_in[7];
    const float* K1       = (const float*)d_in[8];
    const float* Wd1      = (const float*)d_in[9];
    const float* K2       = (const float*)d_in[10];
    const float* Wd2      = (const float*)d_in[11];
    const float* WdBack   = (const float*)d_in[12];
    const float* w_rho1   = (const float*)d_in[13];
    const float* Kmap     = (const float*)d_in[14];

    float* ws   = (float*)d_ws;
    float* pbuf  = ws;                       // 1024 (single buffer: own-row updates)
    float* feat  = ws + 2048;                // 98304  [512][192]
    float* out1  = ws + 100352;              // 32768
    float* out2  = ws + 133120;              // 32768
    float* w4    = ws + 178176;              // 131072
    int*   bin4  = (int*)(ws + 309248);      // 131072 ints
    float4* KTv  = (float4*)(ws + 440320);   // 73728 floats
    float4* KT1  = (float4*)(ws + 514048);   // 24576 floats
    float4* KT2  = (float4*)(ws + 538624);   // 9216 floats
    float* Hv    = ws + 547840;              // 1572864 [512][48][64]
    float* H1    = ws + 2120704;             // 1572864
    float* H2    = ws + 3693568;             // 589824  [512][48][24]
    float* out   = (float*)d_out;

    hipMemcpyAsync(pbuf, in_p, NB * NV * 2 * sizeof(float),
                   hipMemcpyDeviceToDevice, stream);
    hipMemcpyAsync(feat, in_feat, NB * NV * 24 * KR * sizeof(float),
                   hipMemcpyDeviceToDevice, stream);

    k_trans<<<105, 256, 0, stream>>>(Kv, K1, K2, KTv, KT1, KT2);
    k_H0<<<NB * NV, 256, 0, stream>>>(feat, KTv, Hv);

    // step 0 decode (p_0, feat_0, Hv_0 ready)
    k_B<<<NB * NV, 256, 0, stream>>>(pbuf, car_mask, feat, Hv, WdV, w4, bin4, KT1, out1, H1);
    k_C<<<NB * NV, 256, 0, stream>>>(out1, H1, Wd1, w4, bin4, KT2, out2, H2);

    for (int t = 1; t < 30; ++t) {
        k_A<<<NB * NV, 256, 0, stream>>>(t, pbuf, out2, H2, Wd2, w4, bin4, feat,
                                         w_rho1, WdBack, Kmap, map_p, map_feat,
                                         map_mask, KTv, Hv, out);
        k_B<<<NB * NV, 256, 0, stream>>>(pbuf, car_mask, feat, Hv, WdV, w4, bin4, KT1, out1, H1);
        k_C<<<NB * NV, 256, 0, stream>>>(out1, H1, Wd1, w4, bin4, KT2, out2, H2);
    }
    k_fin<<<NB * NV, 256, 0, stream>>>(pbuf, out2, H2, Wd2, w4, bin4, w_rho1, out);
}